// Round 2
// baseline (776.236 us; speedup 1.0000x reference)
//
#include <hip/hip_runtime.h>
#include <stdint.h>

#define NSTEPS 40
#define SBS 264   // LDS state-row stride in elements (256 + 8 pad; 528 B, 16B-aligned)

typedef float    floatx4  __attribute__((ext_vector_type(4)));
typedef __bf16   bf16x8   __attribute__((ext_vector_type(8)));
typedef __bf16   bf16x4   __attribute__((ext_vector_type(4)));
typedef uint32_t uint32x2 __attribute__((ext_vector_type(2)));

__device__ __forceinline__ __bf16 f2bf(float f){
  union { float f; uint32_t u; } v; v.f = f;
  uint32_t r = v.u + 0x7FFFu + ((v.u >> 16) & 1u);   // RNE (prep kernels only)
  union { uint16_t s; __bf16 b; } o; o.s = (uint16_t)(r >> 16);
  return o.b;
}
__device__ __forceinline__ float bf2f(__bf16 b){
  union { uint16_t s; __bf16 b; } i; i.b = b;
  union { uint32_t u; float f; } o; o.u = ((uint32_t)i.s) << 16;
  return o.f;
}
__device__ __forceinline__ uint32_t cvt_pk_bf16(float lo, float hi){
  uint32_t d;
  asm("v_cvt_pk_bf16_f32 %0, %1, %2" : "=v"(d) : "v"(lo), "v"(hi));
  return d;
}
// tanh(x) = 1 - 2/(e^{2x}+1);  e^{2x} = 2^{x * 2*log2(e)}.  2 trans + 3 VALU.
__device__ __forceinline__ float fast_tanh(float x){
  float e;
  asm("v_exp_f32 %0, %1" : "=v"(e) : "v"(x * 2.885390082f));
  return __builtin_fmaf(-2.0f, __builtin_amdgcn_rcpf(e + 1.0f), 1.0f);
}

// ---- prep1: bf16-cast + transpose weights; beta = b2 @ W1 (fp32) ----
__global__ void prep_kernel(const float* __restrict__ Ws,
                            const float* __restrict__ W1,
                            const float* __restrict__ W2,
                            const float* __restrict__ b2,
                            __bf16* __restrict__ WsT,
                            __bf16* __restrict__ W1T,
                            __bf16* __restrict__ W2T,
                            float* __restrict__ beta){
  int tid = blockIdx.x * blockDim.x + threadIdx.x;
  int stride = gridDim.x * blockDim.x;
  for (int i = tid; i < 512*256; i += stride){
    int k = i >> 8, n = i & 255;
    WsT[n*512 + k] = f2bf(Ws[i]);
  }
  for (int i = tid; i < 256*256; i += stride){
    int k = i >> 8, n = i & 255;
    W1T[n*256 + k] = f2bf(W1[i]);
    W2T[n*256 + k] = f2bf(W2[i]);
  }
  if (blockIdx.x == 0){
    int j = threadIdx.x;            // 256 threads
    float acc = 0.f;
    for (int l = 0; l < 256; ++l)
      acc = __builtin_fmaf(b2[l], W1[l*256 + j], acc);
    beta[j] = acc;
  }
}

// ---- prep2: MT[j][i] = (W2@W1)[i][j] (fp32 dot, bf16 store) ----
__global__ void prep_mt(const float* __restrict__ W1,
                        const float* __restrict__ W2,
                        __bf16* __restrict__ MT){
  __shared__ float w2row[256];
  const int i = blockIdx.x;
  const int j = threadIdx.x;
  w2row[j] = W2[i*256 + j];
  __syncthreads();
  float acc = 0.f;
  for (int l = 0; l < 256; ++l)
    acc = __builtin_fmaf(w2row[l], W1[l*256 + j], acc);
  MT[j*256 + i] = f2bf(acc);
}

// Fused ODE kernel, round 13: FIX REGISTER PLACEMENT (r12 tile kept).
// r12's regression diagnosis: "+v" pins forced Mf's 128 regs into ALL arch
// VGPRs (VGPR_Count==128); Y/sM/w/p/temps spilled to AGPRs with
// v_accvgpr_read/write shuttles on every VALU op -> VALU issue +17%.
// Fix: pin Mf/betav with the "a" (AGPR) constraint. gfx950 MFMA reads A/B
// from AGPRs natively (zero copy), freeing all 128 VGPRs for hot VALU state.
// Also: wt (time row of W1) resident in 16 VGPRs (drops 4 ds_read/slot);
// tanh forced to the minimal v_exp+v_rcp path.
__global__ __launch_bounds__(256, 2)
void ode_kernel(const float* __restrict__ x,
                const float* __restrict__ b_state,
                const float* __restrict__ W1full,   // 257x256 fp32 (row 256 = t row)
                const float* __restrict__ b1,
                const float* __restrict__ b2,
                const float* __restrict__ Wout,     // 256x18 fp32
                const float* __restrict__ bout,
                const __bf16* __restrict__ WsT,     // [256][512]
                const __bf16* __restrict__ W1Tg,    // [256][256]
                const __bf16* __restrict__ W2Tg,    // [256][256]
                const __bf16* __restrict__ MTg,     // [256][256]
                const float* __restrict__ betag,    // [256]
                float* __restrict__ out)
{
  __shared__ __align__(16) __bf16 lds_sb0[16*SBS];   // 8.25 KB  z double-buffer A
  __shared__ __align__(16) __bf16 lds_sb1[16*SBS];   // 8.25 KB  z double-buffer B
  __shared__ __align__(16) __bf16 lds_h0[16*SBS];    // 8.25 KB  h0 (kept to epilogue)

  const int tid  = threadIdx.x;
  const int wave = tid >> 6;       // 0..3
  const int lane = tid & 63;
  const int c16  = lane & 15;      // batch col within tile
  const int q    = lane >> 4;      // 0..3
  const int L0   = wave * 64;      // this wave's latent-row base (64 rows)
  const int m0   = blockIdx.x * 16;

  // ---- addressing ----
  int arow[4];
  #pragma unroll
  for (int mt = 0; mt < 4; ++mt) arow[mt] = L0 + mt*16 + c16;  // A-frag rows
  const int brow  = c16 * SBS;     // B batch-row base in z tiles
  const int rbase = L0 + 4*q;      // C/D latent-row base (mt adds 16)

  const float dt  = 1.0f / NSTEPS;
  const float hdt = 0.5f * dt;
  const float dt6 = dt / 6.0f;
  const floatx4 vzero = {0.f, 0.f, 0.f, 0.f};

  // ---- resident wt (time row of W_dyn1), 16 VGPRs ----
  floatx4 wtv[4];
  #pragma unroll
  for (int mt = 0; mt < 4; ++mt)
    wtv[mt] = *(const floatx4*)&W1full[256*256 + rbase + mt*16];

  // ---- phase 0: h0 = tanh(x@Ws + bs) -> lds_h0 ----
  {
    floatx4 p0[4];
    #pragma unroll
    for (int mt = 0; mt < 4; ++mt)
      p0[mt] = *(const floatx4*)&b_state[rbase + mt*16];
    #pragma unroll 1
    for (int kt = 0; kt < 16; ++kt){
      const float* px = &x[(size_t)(m0 + c16)*512 + kt*32 + q*8];
      floatx4 f0 = *(const floatx4*)px;
      floatx4 f1 = *(const floatx4*)(px + 4);
      union { uint32_t u[4]; bf16x8 v; } pk;
      pk.u[0] = cvt_pk_bf16(f0[0], f0[1]);
      pk.u[1] = cvt_pk_bf16(f0[2], f0[3]);
      pk.u[2] = cvt_pk_bf16(f1[0], f1[1]);
      pk.u[3] = cvt_pk_bf16(f1[2], f1[3]);
      bf16x8 b = pk.v;
      #pragma unroll
      for (int mt = 0; mt < 4; ++mt){
        bf16x8 a = *(const bf16x8*)&WsT[arow[mt]*512 + kt*32 + q*8];
        p0[mt] = __builtin_amdgcn_mfma_f32_16x16x32_bf16(a, b, p0[mt], 0, 0, 0);
      }
    }
    #pragma unroll
    for (int mt = 0; mt < 4; ++mt){
      float v0 = fast_tanh(p0[mt][0]);
      float v1 = fast_tanh(p0[mt][1]);
      float v2 = fast_tanh(p0[mt][2]);
      float v3 = fast_tanh(p0[mt][3]);
      uint32x2 wv = { cvt_pk_bf16(v0, v1), cvt_pk_bf16(v2, v3) };
      *(uint32x2*)&lds_h0[brow + rbase + mt*16] = wv;
    }
  }
  __syncthreads();

  // ---- Y = h0 @ W1 + b1 (b1 folded into the carried state) ----
  floatx4 Y[4];
  #pragma unroll
  for (int mt = 0; mt < 4; ++mt)
    Y[mt] = *(const floatx4*)&b1[rbase + mt*16];
  #pragma unroll
  for (int kt = 0; kt < 8; ++kt){
    bf16x8 b = *(const bf16x8*)&lds_h0[brow + kt*32 + q*8];
    #pragma unroll
    for (int mt = 0; mt < 4; ++mt){
      bf16x8 a = *(const bf16x8*)&W1Tg[arow[mt]*256 + kt*32 + q*8];
      Y[mt] = __builtin_amdgcn_mfma_f32_16x16x32_bf16(a, b, Y[mt], 0, 0, 0);
    }
  }

  // ---- resident M^T fragments + beta: pinned to AGPRs ("a" constraint).
  //      MFMA consumes A-operands from AGPRs natively on gfx950 -> no copies,
  //      and the full 128-VGPR arch file stays free for hot VALU state. ----
  bf16x8 Mf[4][8];
  #pragma unroll
  for (int mt = 0; mt < 4; ++mt)
    #pragma unroll
    for (int kt = 0; kt < 8; ++kt)
      Mf[mt][kt] = *(const bf16x8*)&MTg[arow[mt]*256 + kt*32 + q*8];
  floatx4 betav[4];
  #pragma unroll
  for (int mt = 0; mt < 4; ++mt)
    betav[mt] = *(const floatx4*)&betag[rbase + mt*16];
  #pragma unroll
  for (int mt = 0; mt < 4; ++mt){
    #pragma unroll
    for (int kt = 0; kt < 8; ++kt)
      asm volatile("" : "+a"(Mf[mt][kt]));
    asm volatile("" : "+a"(betav[mt]));
  }

  // ---- slot 0: z0 = tanh(Y) (t=0, cin=0), w = z0 -> SB0 ----
  floatx4 w[4], sM[4];
  #pragma unroll
  for (int mt = 0; mt < 4; ++mt){
    floatx4 zv;
    #pragma unroll
    for (int r = 0; r < 4; ++r) zv[r] = fast_tanh(Y[mt][r]);
    w[mt]  = zv;
    sM[mt] = vzero;
    uint32x2 wv = { cvt_pk_bf16(zv[0], zv[1]), cvt_pk_bf16(zv[2], zv[3]) };
    *(uint32x2*)&lds_sb0[brow + rbase + mt*16] = wv;
  }
  __syncthreads();

  // ---- main loop: slots i = 1..159, ONE GEMM + ONE barrier each ----
  #pragma unroll 1
  for (int i = 1; i < NSTEPS*4; ++i){
    const int e = i & 3;
    const float cin = (e == 0) ? 0.0f : ((e == 3) ? dt : hdt);
    const float te  = dt * (float)(i >> 2) + cin;
    const float wz  = (e == 1 || e == 2) ? 2.0f : 1.0f;
    const __bf16* sbR = ((i & 1) == 1) ? lds_sb0 : lds_sb1;  // holds z_{i-1}
    __bf16*       sbW = ((i & 1) == 1) ? lds_sb1 : lds_sb0;  // gets  z_i

    // GEMM: p = beta + z_{i-1} @ M   (A = M^T resident in AGPRs)
    floatx4 p[4];
    #pragma unroll
    for (int mt = 0; mt < 4; ++mt) p[mt] = betav[mt];
    #pragma unroll
    for (int kt = 0; kt < 8; ++kt){
      bf16x8 b = *(const bf16x8*)&sbR[brow + kt*32 + q*8];
      #pragma unroll
      for (int mt = 0; mt < 4; ++mt)
        p[mt] = __builtin_amdgcn_mfma_f32_16x16x32_bf16(Mf[mt][kt], b, p[mt], 0, 0, 0);
    }

    // RK4 bookkeeping (p = q_{i-1} + beta); vector form -> v_pk_fma_f32
    if (e == 0){
      #pragma unroll
      for (int mt = 0; mt < 4; ++mt)
        Y[mt] += dt6 * (sM[mt] + p[mt]);
    } else if (e == 1){
      #pragma unroll
      for (int mt = 0; mt < 4; ++mt) sM[mt] = p[mt];
    } else {
      #pragma unroll
      for (int mt = 0; mt < 4; ++mt) sM[mt] += 2.0f * p[mt];
    }

    // z_i = tanh(Y + cin*p + te*wt); w += wz*z; write -> sbW
    #pragma unroll
    for (int mt = 0; mt < 4; ++mt){
      floatx4 argv = Y[mt] + p[mt]*cin + wtv[mt]*te;
      floatx4 zv;
      #pragma unroll
      for (int r = 0; r < 4; ++r) zv[r] = fast_tanh(argv[r]);
      w[mt] = zv*wz + w[mt];
      uint32x2 wv = { cvt_pk_bf16(zv[0], zv[1]), cvt_pk_bf16(zv[2], zv[3]) };
      *(uint32x2*)&sbW[brow + rbase + mt*16] = wv;
    }
    __syncthreads();
  }

  // ---- epilogue: h_T = h0 + (dt6*w) @ W2 + b2, then out = h_T @ Wout ----
  // pack dt6*w -> SB0 (z_158 dead; its readers finished before slot-159 barrier)
  #pragma unroll
  for (int mt = 0; mt < 4; ++mt){
    floatx4 wv4 = w[mt] * dt6;
    uint32x2 wv = { cvt_pk_bf16(wv4[0], wv4[1]), cvt_pk_bf16(wv4[2], wv4[3]) };
    *(uint32x2*)&lds_sb0[brow + rbase + mt*16] = wv;
  }
  __syncthreads();
  {
    floatx4 hF[4];
    #pragma unroll
    for (int mt = 0; mt < 4; ++mt)
      hF[mt] = *(const floatx4*)&b2[rbase + mt*16];
    #pragma unroll
    for (int kt = 0; kt < 8; ++kt){
      bf16x8 b = *(const bf16x8*)&lds_sb0[brow + kt*32 + q*8];
      #pragma unroll
      for (int mt = 0; mt < 4; ++mt){
        bf16x8 a = *(const bf16x8*)&W2Tg[arow[mt]*256 + kt*32 + q*8];
        hF[mt] = __builtin_amdgcn_mfma_f32_16x16x32_bf16(a, b, hF[mt], 0, 0, 0);
      }
    }
    // + h0, write h_T -> SB1 (z_159 never read; safe to overwrite)
    #pragma unroll
    for (int mt = 0; mt < 4; ++mt){
      bf16x4 h0v = *(const bf16x4*)&lds_h0[brow + rbase + mt*16];
      #pragma unroll
      for (int r = 0; r < 4; ++r) hF[mt][r] += bf2f(h0v[r]);
      uint32x2 wv = { cvt_pk_bf16(hF[mt][0], hF[mt][1]),
                      cvt_pk_bf16(hF[mt][2], hF[mt][3]) };
      *(uint32x2*)&lds_sb1[brow + rbase + mt*16] = wv;
    }
  }
  __syncthreads();
  {
    const int r  = tid & 15;         // batch row within block
    const int og = tid >> 4;         // 0..15: output col; og<2 also does og+16
    float acc0 = 0.f;
    for (int c = 0; c < 32; ++c){
      bf16x8 h8 = *(const bf16x8*)&lds_sb1[r*SBS + c*8];
      #pragma unroll
      for (int j = 0; j < 8; ++j)
        acc0 += bf2f(h8[j]) * Wout[(c*8 + j)*18 + og];
    }
    out[(size_t)(m0 + r)*18 + og] = acc0 + bout[og];
    if (og < 2){
      const int o2 = 16 + og;
      float acc1 = 0.f;
      for (int c = 0; c < 32; ++c){
        bf16x8 h8 = *(const bf16x8*)&lds_sb1[r*SBS + c*8];
        #pragma unroll
        for (int j = 0; j < 8; ++j)
          acc1 += bf2f(h8[j]) * Wout[(c*8 + j)*18 + o2];
      }
      out[(size_t)(m0 + r)*18 + o2] = acc1 + bout[o2];
    }
  }
}

extern "C" void kernel_launch(void* const* d_in, const int* in_sizes, int n_in,
                              void* d_out, int out_size, void* d_ws, size_t ws_size,
                              hipStream_t stream){
  const float* x   = (const float*)d_in[0];
  const float* Ws  = (const float*)d_in[1];
  const float* bs  = (const float*)d_in[2];
  const float* W1  = (const float*)d_in[3];
  const float* b1  = (const float*)d_in[4];
  const float* W2  = (const float*)d_in[5];
  const float* b2  = (const float*)d_in[6];
  const float* Wo  = (const float*)d_in[7];
  const float* bo  = (const float*)d_in[8];
  float* out = (float*)d_out;

  __bf16* WsT  = (__bf16*)d_ws;          // 256x512 bf16 = 256 KB
  __bf16* W1T  = WsT + 512*256;          // 256x256 bf16 = 128 KB
  __bf16* W2T  = W1T + 256*256;          // 256x256 bf16 = 128 KB
  __bf16* MT   = W2T + 256*256;          // 256x256 bf16 = 128 KB
  float*  beta = (float*)(MT + 256*256); // 256 fp32 = 1 KB

  prep_kernel<<<128, 256, 0, stream>>>(Ws, W1, W2, b2, WsT, W1T, W2T, beta);
  prep_mt<<<256, 256, 0, stream>>>(W1, W2, MT);
  ode_kernel<<<1024, 256, 0, stream>>>(x, bs, W1, b1, b2, Wo, bo,
                                       WsT, W1T, W2T, MT, beta, out);
}

// Round 3
// 607.436 us; speedup vs baseline: 1.2779x; 1.2779x over previous
//
#include <hip/hip_runtime.h>
#include <stdint.h>

#define NSTEPS 40
#define SBS 264   // LDS state-row stride in elements (256 + 8 pad; 528 B, 16B-aligned)

typedef float    floatx4  __attribute__((ext_vector_type(4)));
typedef __bf16   bf16x8   __attribute__((ext_vector_type(8)));
typedef __bf16   bf16x4   __attribute__((ext_vector_type(4)));
typedef uint32_t uint32x2 __attribute__((ext_vector_type(2)));

__device__ __forceinline__ __bf16 f2bf(float f){
  union { float f; uint32_t u; } v; v.f = f;
  uint32_t r = v.u + 0x7FFFu + ((v.u >> 16) & 1u);   // RNE (prep kernels only)
  union { uint16_t s; __bf16 b; } o; o.s = (uint16_t)(r >> 16);
  return o.b;
}
__device__ __forceinline__ float bf2f(__bf16 b){
  union { uint16_t s; __bf16 b; } i; i.b = b;
  union { uint32_t u; float f; } o; o.u = ((uint32_t)i.s) << 16;
  return o.f;
}
__device__ __forceinline__ uint32_t cvt_pk_bf16(float lo, float hi){
  uint32_t d;
  asm("v_cvt_pk_bf16_f32 %0, %1, %2" : "=v"(d) : "v"(lo), "v"(hi));
  return d;
}
// tanh(x) = 1 - 2/(e^{2x}+1);  e^{2x} = 2^{x * 2*log2(e)}.  2 trans + 3 VALU.
__device__ __forceinline__ float fast_tanh(float x){
  float e;
  asm("v_exp_f32 %0, %1" : "=v"(e) : "v"(x * 2.885390082f));
  return __builtin_fmaf(-2.0f, __builtin_amdgcn_rcpf(e + 1.0f), 1.0f);
}

// ---- prep1: bf16-cast + transpose weights; beta = b2 @ W1 (fp32) ----
__global__ void prep_kernel(const float* __restrict__ Ws,
                            const float* __restrict__ W1,
                            const float* __restrict__ W2,
                            const float* __restrict__ b2,
                            __bf16* __restrict__ WsT,
                            __bf16* __restrict__ W1T,
                            __bf16* __restrict__ W2T,
                            float* __restrict__ beta){
  int tid = blockIdx.x * blockDim.x + threadIdx.x;
  int stride = gridDim.x * blockDim.x;
  for (int i = tid; i < 512*256; i += stride){
    int k = i >> 8, n = i & 255;
    WsT[n*512 + k] = f2bf(Ws[i]);
  }
  for (int i = tid; i < 256*256; i += stride){
    int k = i >> 8, n = i & 255;
    W1T[n*256 + k] = f2bf(W1[i]);
    W2T[n*256 + k] = f2bf(W2[i]);
  }
  if (blockIdx.x == 0){
    int j = threadIdx.x;            // 256 threads
    float acc = 0.f;
    for (int l = 0; l < 256; ++l)
      acc = __builtin_fmaf(b2[l], W1[l*256 + j], acc);
    beta[j] = acc;
  }
}

// ---- prep2: MT[j][i] = (W2@W1)[i][j] (fp32 dot, bf16 store) ----
__global__ void prep_mt(const float* __restrict__ W1,
                        const float* __restrict__ W2,
                        __bf16* __restrict__ MT){
  __shared__ float w2row[256];
  const int i = blockIdx.x;
  const int j = threadIdx.x;
  w2row[j] = W2[i*256 + j];
  __syncthreads();
  float acc = 0.f;
  for (int l = 0; l < 256; ++l)
    acc = __builtin_fmaf(w2row[l], W1[l*256 + j], acc);
  MT[j*256 + i] = f2bf(acc);
}

// Fused ODE kernel, round 14: FIT THE REGISTER FILE EXACTLY.
// r13 post-mortem: pinned AGPRs (Mf 128 + betav 16 = 144) + 128 arch VGPRs
// = 272 > 256 unified regs/wave @ 2 waves/SIMD -> scratch spill (WRITE_SIZE
// 27 MB). Fix:
//  - gamma fold: arg = Y + cin*p' + te*(beta+wt) since te = s*dt + cin.
//    ONE resident 16-reg vector replaces betav+wtv (32 regs); p init = 0.
//    (Y carries pure q' sums; dropped dt*beta per step is absorbed by
//    te*gamma. Bit-equivalent here since b2=0 -> beta=0.)
//  - pin ONLY Mf (exactly 128 AGPRs). Hot fp32 state (Y/sM/w/gamma/p ~110)
//    stays in arch VGPRs. Total ~238 < 256: no spill, no accvgpr shuttles.
__global__ __launch_bounds__(256, 2)
void ode_kernel(const float* __restrict__ x,
                const float* __restrict__ b_state,
                const float* __restrict__ W1full,   // 257x256 fp32 (row 256 = t row)
                const float* __restrict__ b1,
                const float* __restrict__ b2,
                const float* __restrict__ Wout,     // 256x18 fp32
                const float* __restrict__ bout,
                const __bf16* __restrict__ WsT,     // [256][512]
                const __bf16* __restrict__ W1Tg,    // [256][256]
                const __bf16* __restrict__ W2Tg,    // [256][256]
                const __bf16* __restrict__ MTg,     // [256][256]
                const float* __restrict__ betag,    // [256]
                float* __restrict__ out)
{
  __shared__ __align__(16) __bf16 lds_sb0[16*SBS];   // 8.25 KB  z double-buffer A
  __shared__ __align__(16) __bf16 lds_sb1[16*SBS];   // 8.25 KB  z double-buffer B
  __shared__ __align__(16) __bf16 lds_h0[16*SBS];    // 8.25 KB  h0 (kept to epilogue)

  const int tid  = threadIdx.x;
  const int wave = tid >> 6;       // 0..3
  const int lane = tid & 63;
  const int c16  = lane & 15;      // batch col within tile
  const int q    = lane >> 4;      // 0..3
  const int L0   = wave * 64;      // this wave's latent-row base (64 rows)
  const int m0   = blockIdx.x * 16;

  // ---- addressing ----
  int arow[4];
  #pragma unroll
  for (int mt = 0; mt < 4; ++mt) arow[mt] = L0 + mt*16 + c16;  // A-frag rows
  const int brow  = c16 * SBS;     // B batch-row base in z tiles
  const int rbase = L0 + 4*q;      // C/D latent-row base (mt adds 16)

  const float dt  = 1.0f / NSTEPS;
  const float hdt = 0.5f * dt;
  const float dt6 = dt / 6.0f;
  const floatx4 vzero = {0.f, 0.f, 0.f, 0.f};

  // ---- resident gamma = beta + wt (time row of W_dyn1), 16 VGPRs ----
  floatx4 gam[4];
  #pragma unroll
  for (int mt = 0; mt < 4; ++mt){
    floatx4 bv = *(const floatx4*)&betag[rbase + mt*16];
    floatx4 wv = *(const floatx4*)&W1full[256*256 + rbase + mt*16];
    gam[mt] = bv + wv;
  }

  // ---- phase 0: h0 = tanh(x@Ws + bs) -> lds_h0 ----
  {
    floatx4 p0[4];
    #pragma unroll
    for (int mt = 0; mt < 4; ++mt)
      p0[mt] = *(const floatx4*)&b_state[rbase + mt*16];
    #pragma unroll 1
    for (int kt = 0; kt < 16; ++kt){
      const float* px = &x[(size_t)(m0 + c16)*512 + kt*32 + q*8];
      floatx4 f0 = *(const floatx4*)px;
      floatx4 f1 = *(const floatx4*)(px + 4);
      union { uint32_t u[4]; bf16x8 v; } pk;
      pk.u[0] = cvt_pk_bf16(f0[0], f0[1]);
      pk.u[1] = cvt_pk_bf16(f0[2], f0[3]);
      pk.u[2] = cvt_pk_bf16(f1[0], f1[1]);
      pk.u[3] = cvt_pk_bf16(f1[2], f1[3]);
      bf16x8 b = pk.v;
      #pragma unroll
      for (int mt = 0; mt < 4; ++mt){
        bf16x8 a = *(const bf16x8*)&WsT[arow[mt]*512 + kt*32 + q*8];
        p0[mt] = __builtin_amdgcn_mfma_f32_16x16x32_bf16(a, b, p0[mt], 0, 0, 0);
      }
    }
    #pragma unroll
    for (int mt = 0; mt < 4; ++mt){
      float v0 = fast_tanh(p0[mt][0]);
      float v1 = fast_tanh(p0[mt][1]);
      float v2 = fast_tanh(p0[mt][2]);
      float v3 = fast_tanh(p0[mt][3]);
      uint32x2 wv = { cvt_pk_bf16(v0, v1), cvt_pk_bf16(v2, v3) };
      *(uint32x2*)&lds_h0[brow + rbase + mt*16] = wv;
    }
  }
  __syncthreads();

  // ---- Y = h0 @ W1 + b1 (b1 folded into the carried state) ----
  floatx4 Y[4];
  #pragma unroll
  for (int mt = 0; mt < 4; ++mt)
    Y[mt] = *(const floatx4*)&b1[rbase + mt*16];
  #pragma unroll
  for (int kt = 0; kt < 8; ++kt){
    bf16x8 b = *(const bf16x8*)&lds_h0[brow + kt*32 + q*8];
    #pragma unroll
    for (int mt = 0; mt < 4; ++mt){
      bf16x8 a = *(const bf16x8*)&W1Tg[arow[mt]*256 + kt*32 + q*8];
      Y[mt] = __builtin_amdgcn_mfma_f32_16x16x32_bf16(a, b, Y[mt], 0, 0, 0);
    }
  }

  // ---- resident M^T fragments: pinned to AGPRs (exactly 128).
  //      MFMA reads A from AGPR natively; all VGPRs stay free for VALU state. ----
  bf16x8 Mf[4][8];
  #pragma unroll
  for (int mt = 0; mt < 4; ++mt)
    #pragma unroll
    for (int kt = 0; kt < 8; ++kt)
      Mf[mt][kt] = *(const bf16x8*)&MTg[arow[mt]*256 + kt*32 + q*8];
  #pragma unroll
  for (int mt = 0; mt < 4; ++mt)
    #pragma unroll
    for (int kt = 0; kt < 8; ++kt)
      asm volatile("" : "+a"(Mf[mt][kt]));

  // ---- slot 0: z0 = tanh(Y) (t=0, cin=0, te=0), w = z0 -> SB0 ----
  floatx4 w[4], sM[4];
  #pragma unroll
  for (int mt = 0; mt < 4; ++mt){
    floatx4 zv;
    #pragma unroll
    for (int r = 0; r < 4; ++r) zv[r] = fast_tanh(Y[mt][r]);
    w[mt]  = zv;
    sM[mt] = vzero;
    uint32x2 wv = { cvt_pk_bf16(zv[0], zv[1]), cvt_pk_bf16(zv[2], zv[3]) };
    *(uint32x2*)&lds_sb0[brow + rbase + mt*16] = wv;
  }
  __syncthreads();

  // ---- main loop: slots i = 1..159, ONE GEMM + ONE barrier each ----
  #pragma unroll 1
  for (int i = 1; i < NSTEPS*4; ++i){
    const int e = i & 3;
    const float cin = (e == 0) ? 0.0f : ((e == 3) ? dt : hdt);
    const float te  = dt * (float)(i >> 2) + cin;
    const float wz  = (e == 1 || e == 2) ? 2.0f : 1.0f;
    const __bf16* sbR = ((i & 1) == 1) ? lds_sb0 : lds_sb1;  // holds z_{i-1}
    __bf16*       sbW = ((i & 1) == 1) ? lds_sb1 : lds_sb0;  // gets  z_i

    // GEMM: p = z_{i-1} @ M   (pure; A = M^T resident in AGPRs)
    floatx4 p[4];
    #pragma unroll
    for (int mt = 0; mt < 4; ++mt) p[mt] = vzero;
    #pragma unroll
    for (int kt = 0; kt < 8; ++kt){
      bf16x8 b = *(const bf16x8*)&sbR[brow + kt*32 + q*8];
      #pragma unroll
      for (int mt = 0; mt < 4; ++mt)
        p[mt] = __builtin_amdgcn_mfma_f32_16x16x32_bf16(Mf[mt][kt], b, p[mt], 0, 0, 0);
    }

    // RK4 bookkeeping (pure q sums; beta absorbed by te*gamma)
    if (e == 0){
      #pragma unroll
      for (int mt = 0; mt < 4; ++mt)
        Y[mt] += dt6 * (sM[mt] + p[mt]);
    } else if (e == 1){
      #pragma unroll
      for (int mt = 0; mt < 4; ++mt) sM[mt] = p[mt];
    } else {
      #pragma unroll
      for (int mt = 0; mt < 4; ++mt) sM[mt] += 2.0f * p[mt];
    }

    // z_i = tanh(Y + cin*p + te*gamma); w += wz*z; write -> sbW
    #pragma unroll
    for (int mt = 0; mt < 4; ++mt){
      floatx4 argv = Y[mt] + p[mt]*cin + gam[mt]*te;
      floatx4 zv;
      #pragma unroll
      for (int r = 0; r < 4; ++r) zv[r] = fast_tanh(argv[r]);
      w[mt] = zv*wz + w[mt];
      uint32x2 wv = { cvt_pk_bf16(zv[0], zv[1]), cvt_pk_bf16(zv[2], zv[3]) };
      *(uint32x2*)&sbW[brow + rbase + mt*16] = wv;
    }
    __syncthreads();
  }

  // ---- epilogue: h_T = h0 + (dt6*w) @ W2 + b2, then out = h_T @ Wout ----
  // pack dt6*w -> SB0 (z_158 dead; its readers finished before slot-159 barrier)
  #pragma unroll
  for (int mt = 0; mt < 4; ++mt){
    floatx4 wv4 = w[mt] * dt6;
    uint32x2 wv = { cvt_pk_bf16(wv4[0], wv4[1]), cvt_pk_bf16(wv4[2], wv4[3]) };
    *(uint32x2*)&lds_sb0[brow + rbase + mt*16] = wv;
  }
  __syncthreads();
  {
    floatx4 hF[4];
    #pragma unroll
    for (int mt = 0; mt < 4; ++mt)
      hF[mt] = *(const floatx4*)&b2[rbase + mt*16];
    #pragma unroll
    for (int kt = 0; kt < 8; ++kt){
      bf16x8 b = *(const bf16x8*)&lds_sb0[brow + kt*32 + q*8];
      #pragma unroll
      for (int mt = 0; mt < 4; ++mt){
        bf16x8 a = *(const bf16x8*)&W2Tg[arow[mt]*256 + kt*32 + q*8];
        hF[mt] = __builtin_amdgcn_mfma_f32_16x16x32_bf16(a, b, hF[mt], 0, 0, 0);
      }
    }
    // + h0, write h_T -> SB1 (z_159 never read; safe to overwrite)
    #pragma unroll
    for (int mt = 0; mt < 4; ++mt){
      bf16x4 h0v = *(const bf16x4*)&lds_h0[brow + rbase + mt*16];
      #pragma unroll
      for (int r = 0; r < 4; ++r) hF[mt][r] += bf2f(h0v[r]);
      uint32x2 wv = { cvt_pk_bf16(hF[mt][0], hF[mt][1]),
                      cvt_pk_bf16(hF[mt][2], hF[mt][3]) };
      *(uint32x2*)&lds_sb1[brow + rbase + mt*16] = wv;
    }
  }
  __syncthreads();
  {
    const int r  = tid & 15;         // batch row within block
    const int og = tid >> 4;         // 0..15: output col; og<2 also does og+16
    float acc0 = 0.f;
    for (int c = 0; c < 32; ++c){
      bf16x8 h8 = *(const bf16x8*)&lds_sb1[r*SBS + c*8];
      #pragma unroll
      for (int j = 0; j < 8; ++j)
        acc0 += bf2f(h8[j]) * Wout[(c*8 + j)*18 + og];
    }
    out[(size_t)(m0 + r)*18 + og] = acc0 + bout[og];
    if (og < 2){
      const int o2 = 16 + og;
      float acc1 = 0.f;
      for (int c = 0; c < 32; ++c){
        bf16x8 h8 = *(const bf16x8*)&lds_sb1[r*SBS + c*8];
        #pragma unroll
        for (int j = 0; j < 8; ++j)
          acc1 += bf2f(h8[j]) * Wout[(c*8 + j)*18 + o2];
      }
      out[(size_t)(m0 + r)*18 + o2] = acc1 + bout[o2];
    }
  }
}

extern "C" void kernel_launch(void* const* d_in, const int* in_sizes, int n_in,
                              void* d_out, int out_size, void* d_ws, size_t ws_size,
                              hipStream_t stream){
  const float* x   = (const float*)d_in[0];
  const float* Ws  = (const float*)d_in[1];
  const float* bs  = (const float*)d_in[2];
  const float* W1  = (const float*)d_in[3];
  const float* b1  = (const float*)d_in[4];
  const float* W2  = (const float*)d_in[5];
  const float* b2  = (const float*)d_in[6];
  const float* Wo  = (const float*)d_in[7];
  const float* bo  = (const float*)d_in[8];
  float* out = (float*)d_out;

  __bf16* WsT  = (__bf16*)d_ws;          // 256x512 bf16 = 256 KB
  __bf16* W1T  = WsT + 512*256;          // 256x256 bf16 = 128 KB
  __bf16* W2T  = W1T + 256*256;          // 256x256 bf16 = 128 KB
  __bf16* MT   = W2T + 256*256;          // 256x256 bf16 = 128 KB
  float*  beta = (float*)(MT + 256*256); // 256 fp32 = 1 KB

  prep_kernel<<<128, 256, 0, stream>>>(Ws, W1, W2, b2, WsT, W1T, W2T, beta);
  prep_mt<<<256, 256, 0, stream>>>(W1, W2, MT);
  ode_kernel<<<1024, 256, 0, stream>>>(x, bs, W1, b1, b2, Wo, bo,
                                       WsT, W1T, W2T, MT, beta, out);
}

// Round 4
// 573.605 us; speedup vs baseline: 1.3533x; 1.0590x over previous
//
#include <hip/hip_runtime.h>
#include <stdint.h>

#define NSTEPS 40
#define SBS 264   // LDS state-row stride in elements (256 + 8 pad; 528 B, 16B-aligned)

typedef float    floatx4  __attribute__((ext_vector_type(4)));
typedef __bf16   bf16x8   __attribute__((ext_vector_type(8)));
typedef __bf16   bf16x4   __attribute__((ext_vector_type(4)));
typedef uint32_t uint32x2 __attribute__((ext_vector_type(2)));

__device__ __forceinline__ __bf16 f2bf(float f){
  union { float f; uint32_t u; } v; v.f = f;
  uint32_t r = v.u + 0x7FFFu + ((v.u >> 16) & 1u);   // RNE (prep kernels only)
  union { uint16_t s; __bf16 b; } o; o.s = (uint16_t)(r >> 16);
  return o.b;
}
__device__ __forceinline__ float bf2f(__bf16 b){
  union { uint16_t s; __bf16 b; } i; i.b = b;
  union { uint32_t u; float f; } o; o.u = ((uint32_t)i.s) << 16;
  return o.f;
}
__device__ __forceinline__ uint32_t cvt_pk_bf16(float lo, float hi){
  uint32_t d;
  asm("v_cvt_pk_bf16_f32 %0, %1, %2" : "=v"(d) : "v"(lo), "v"(hi));
  return d;
}
// tanh(x) = 1 - 2/(e^{2x}+1);  e^{2x} = 2^{x * 2*log2(e)}.  2 trans + 3 VALU.
__device__ __forceinline__ float fast_tanh(float x){
  float e;
  asm("v_exp_f32 %0, %1" : "=v"(e) : "v"(x * 2.885390082f));
  return __builtin_fmaf(-2.0f, __builtin_amdgcn_rcpf(e + 1.0f), 1.0f);
}

// ---- prep1: bf16-cast + transpose weights; beta = b2 @ W1 (fp32) ----
__global__ void prep_kernel(const float* __restrict__ Ws,
                            const float* __restrict__ W1,
                            const float* __restrict__ W2,
                            const float* __restrict__ b2,
                            __bf16* __restrict__ WsT,
                            __bf16* __restrict__ W1T,
                            __bf16* __restrict__ W2T,
                            float* __restrict__ beta){
  int tid = blockIdx.x * blockDim.x + threadIdx.x;
  int stride = gridDim.x * blockDim.x;
  for (int i = tid; i < 512*256; i += stride){
    int k = i >> 8, n = i & 255;
    WsT[n*512 + k] = f2bf(Ws[i]);
  }
  for (int i = tid; i < 256*256; i += stride){
    int k = i >> 8, n = i & 255;
    W1T[n*256 + k] = f2bf(W1[i]);
    W2T[n*256 + k] = f2bf(W2[i]);
  }
  if (blockIdx.x == 0){
    int j = threadIdx.x;            // 256 threads
    float acc = 0.f;
    for (int l = 0; l < 256; ++l)
      acc = __builtin_fmaf(b2[l], W1[l*256 + j], acc);
    beta[j] = acc;
  }
}

// ---- prep2: MT[j][i] = (W2@W1)[i][j] (fp32 dot, bf16 store) ----
__global__ void prep_mt(const float* __restrict__ W1,
                        const float* __restrict__ W2,
                        __bf16* __restrict__ MT){
  __shared__ float w2row[256];
  const int i = blockIdx.x;
  const int j = threadIdx.x;
  w2row[j] = W2[i*256 + j];
  __syncthreads();
  float acc = 0.f;
  for (int l = 0; l < 256; ++l)
    acc = __builtin_fmaf(w2row[l], W1[l*256 + j], acc);
  MT[j*256 + i] = f2bf(acc);
}

// Fused ODE kernel, round 15: r11 STRUCTURE + INTRA-SLOT MFMA/VALU INTERLEAVE.
// r12-r14 post-mortem: 2-block-per-CU overlap never materialized; occupancy is
// hard-capped at 2 waves/SIMD by resident state. Both r11/r14 lose ~40% of the
// slot to zero overlap between the GEMM phase and the tanh phase (MfmaUtil 26%
// + VALU ~30%, serial). Fix here: split the slot into nt-phases -
//   A: GEMM(nt0,nt1)
//   B: GEMM(nt2,nt3) source-interleaved with tanh/write of nt0,nt1 (indep.)
//   C: tanh/write nt2,nt3; barrier
// plus r14's verified gamma fold (arg = Y + cin*p + te*(beta+wt), b1 in Y,
// pure-p GEMM) which eliminates lds_bias and its per-slot reads entirely.
__global__ __launch_bounds__(512, 2)
void ode_kernel(const float* __restrict__ x,
                const float* __restrict__ b_state,
                const float* __restrict__ W1full,   // 257x256 fp32 (row 256 = t row)
                const float* __restrict__ b1,
                const float* __restrict__ b2,
                const float* __restrict__ Wout,     // 256x18 fp32
                const float* __restrict__ bout,
                const __bf16* __restrict__ WsT,     // [256][512]
                const __bf16* __restrict__ W1Tg,    // [256][256]
                const __bf16* __restrict__ W2Tg,    // [256][256]
                const __bf16* __restrict__ MTg,     // [256][256]
                const float* __restrict__ betag,    // [256]
                float* __restrict__ out)
{
  __shared__ __align__(16) __bf16 lds_sb0[64*SBS];   // 33 KB  z double-buffer A
  __shared__ __align__(16) __bf16 lds_sb1[64*SBS];   // 33 KB  z double-buffer B
  __shared__ __align__(16) __bf16 lds_h0[64*SBS];    // 33 KB  h0 (kept to epilogue)

  const int tid  = threadIdx.x;
  const int wave = tid >> 6;       // 0..7
  const int lane = tid & 63;
  const int c16  = lane & 15;
  const int q    = lane >> 4;      // 0..3
  const int nh0  = wave * 32;      // this wave's y-row base (32 rows)
  const int m0   = blockIdx.x * 64;

  // ---- addressing (padded-linear) ----
  int arow[2];
  #pragma unroll
  for (int mt = 0; mt < 2; ++mt) arow[mt] = nh0 + mt*16 + c16;
  const int browc = c16 * SBS;      // B batch-row base (nt adds 16*SBS)
  const int n04   = nh0 + 4*q;      // C/D row base (mt adds 16)

  const float dt  = 1.0f / NSTEPS;
  const float hdt = 0.5f * dt;
  const float dt6 = dt / 6.0f;
  const floatx4 vzero = {0.f, 0.f, 0.f, 0.f};

  // ---- resident gamma = beta + wt (time row of W_dyn1), 8 VGPRs ----
  floatx4 gam[2];
  #pragma unroll
  for (int mt = 0; mt < 2; ++mt){
    floatx4 bv = *(const floatx4*)&betag[n04 + mt*16];
    floatx4 wv = *(const floatx4*)&W1full[256*256 + n04 + mt*16];
    gam[mt] = bv + wv;
  }

  // ---- resident M fragments (A-operand), 64 regs ----
  bf16x8 Mf[2][8];
  #pragma unroll
  for (int mt = 0; mt < 2; ++mt)
    #pragma unroll
    for (int kt = 0; kt < 8; ++kt)
      Mf[mt][kt] = *(const bf16x8*)&MTg[arow[mt]*256 + kt*32 + q*8];
  #pragma unroll
  for (int mt = 0; mt < 2; ++mt){
    #pragma unroll
    for (int kt = 0; kt < 8; ++kt)
      asm volatile("" : "+v"(Mf[mt][kt]));
    asm volatile("" : "+v"(gam[mt]));
  }

  floatx4 Y[2][4], p[2][4], sM[2][4], w[2][4];

  // ---- phase 0: h0 = tanh(x@Ws + bs) -> lds_h0 ----
  {
    #pragma unroll
    for (int mt = 0; mt < 2; ++mt){
      floatx4 bsv = *(const floatx4*)&b_state[n04 + mt*16];
      #pragma unroll
      for (int nt = 0; nt < 4; ++nt) p[mt][nt] = bsv;
    }
    #pragma unroll 1
    for (int kt = 0; kt < 16; ++kt){
      bf16x8 b[4];
      #pragma unroll
      for (int nt = 0; nt < 4; ++nt){
        const float* px = &x[(size_t)(m0 + nt*16 + c16)*512 + kt*32 + q*8];
        floatx4 f0 = *(const floatx4*)px;
        floatx4 f1 = *(const floatx4*)(px + 4);
        union { uint32_t u[4]; bf16x8 v; } pk;
        pk.u[0] = cvt_pk_bf16(f0[0], f0[1]);
        pk.u[1] = cvt_pk_bf16(f0[2], f0[3]);
        pk.u[2] = cvt_pk_bf16(f1[0], f1[1]);
        pk.u[3] = cvt_pk_bf16(f1[2], f1[3]);
        b[nt] = pk.v;
      }
      #pragma unroll
      for (int mt = 0; mt < 2; ++mt){
        bf16x8 a = *(const bf16x8*)&WsT[arow[mt]*512 + kt*32 + q*8];
        #pragma unroll
        for (int nt = 0; nt < 4; ++nt)
          p[mt][nt] = __builtin_amdgcn_mfma_f32_16x16x32_bf16(a, b[nt], p[mt][nt], 0, 0, 0);
      }
    }
    #pragma unroll
    for (int mt = 0; mt < 2; ++mt)
      #pragma unroll
      for (int nt = 0; nt < 4; ++nt){
        float v0 = fast_tanh(p[mt][nt][0]);
        float v1 = fast_tanh(p[mt][nt][1]);
        float v2 = fast_tanh(p[mt][nt][2]);
        float v3 = fast_tanh(p[mt][nt][3]);
        uint32x2 wv = { cvt_pk_bf16(v0, v1), cvt_pk_bf16(v2, v3) };
        *(uint32x2*)&lds_h0[browc + nt*(16*SBS) + n04 + mt*16] = wv;
      }
  }
  __syncthreads();

  // ---- Y = h0 @ W1 + b1 (b1 folded into carried state), W1 frags transient ----
  {
    bf16x8 W1f[2][8];
    #pragma unroll
    for (int mt = 0; mt < 2; ++mt)
      #pragma unroll
      for (int kt = 0; kt < 8; ++kt)
        W1f[mt][kt] = *(const bf16x8*)&W1Tg[arow[mt]*256 + kt*32 + q*8];
    #pragma unroll
    for (int mt = 0; mt < 2; ++mt){
      floatx4 b1v = *(const floatx4*)&b1[n04 + mt*16];
      #pragma unroll
      for (int nt = 0; nt < 4; ++nt) Y[mt][nt] = b1v;
    }
    #pragma unroll
    for (int kt = 0; kt < 8; ++kt){
      bf16x8 b[4];
      #pragma unroll
      for (int nt = 0; nt < 4; ++nt)
        b[nt] = *(const bf16x8*)&lds_h0[browc + nt*(16*SBS) + kt*32 + q*8];
      #pragma unroll
      for (int mt = 0; mt < 2; ++mt)
        #pragma unroll
        for (int nt = 0; nt < 4; ++nt)
          Y[mt][nt] = __builtin_amdgcn_mfma_f32_16x16x32_bf16(W1f[mt][kt], b[nt], Y[mt][nt], 0, 0, 0);
    }
  }

  // ---- slot 0: z0 = tanh(Y) (t=0: cin=0, te=0), w = z0, write -> SB0 ----
  #pragma unroll
  for (int mt = 0; mt < 2; ++mt)
    #pragma unroll
    for (int nt = 0; nt < 4; ++nt){
      floatx4 zv;
      #pragma unroll
      for (int r = 0; r < 4; ++r) zv[r] = fast_tanh(Y[mt][nt][r]);
      w[mt][nt]  = zv;
      sM[mt][nt] = vzero;
      uint32x2 wv = { cvt_pk_bf16(zv[0], zv[1]), cvt_pk_bf16(zv[2], zv[3]) };
      *(uint32x2*)&lds_sb0[browc + nt*(16*SBS) + n04 + mt*16] = wv;
    }
  __syncthreads();

  // ---- main loop: slots i = 1..159, phased GEMM/VALU interleave ----
  #pragma unroll 1
  for (int i = 1; i < NSTEPS*4; ++i){
    const int e = i & 3;
    const float cin = (e == 0) ? 0.0f : ((e == 3) ? dt : hdt);
    const float te  = dt * (float)(i >> 2) + cin;
    const float wz  = (e == 1 || e == 2) ? 2.0f : 1.0f;
    const __bf16* sbR = ((i & 1) == 1) ? lds_sb0 : lds_sb1;  // holds z_{i-1}
    __bf16*       sbW = ((i & 1) == 1) ? lds_sb1 : lds_sb0;  // gets  z_i

    #pragma unroll
    for (int mt = 0; mt < 2; ++mt)
      #pragma unroll
      for (int nt = 0; nt < 4; ++nt) p[mt][nt] = vzero;

    // ---- region A: GEMM for nt0, nt1 (pure p = z@M) ----
    #pragma unroll
    for (int kt = 0; kt < 8; ++kt){
      bf16x8 b0 = *(const bf16x8*)&sbR[browc + 0*(16*SBS) + kt*32 + q*8];
      bf16x8 b1f = *(const bf16x8*)&sbR[browc + 1*(16*SBS) + kt*32 + q*8];
      p[0][0] = __builtin_amdgcn_mfma_f32_16x16x32_bf16(Mf[0][kt], b0,  p[0][0], 0, 0, 0);
      p[1][0] = __builtin_amdgcn_mfma_f32_16x16x32_bf16(Mf[1][kt], b0,  p[1][0], 0, 0, 0);
      p[0][1] = __builtin_amdgcn_mfma_f32_16x16x32_bf16(Mf[0][kt], b1f, p[0][1], 0, 0, 0);
      p[1][1] = __builtin_amdgcn_mfma_f32_16x16x32_bf16(Mf[1][kt], b1f, p[1][1], 0, 0, 0);
    }

    // bookkeeping for nt0, nt1
    if (e == 0){
      #pragma unroll
      for (int mt = 0; mt < 2; ++mt)
        #pragma unroll
        for (int nt = 0; nt < 2; ++nt)
          Y[mt][nt] += dt6 * (sM[mt][nt] + p[mt][nt]);
    } else if (e == 1){
      #pragma unroll
      for (int mt = 0; mt < 2; ++mt)
        #pragma unroll
        for (int nt = 0; nt < 2; ++nt) sM[mt][nt] = p[mt][nt];
    } else {
      #pragma unroll
      for (int mt = 0; mt < 2; ++mt)
        #pragma unroll
        for (int nt = 0; nt < 2; ++nt) sM[mt][nt] += 2.0f * p[mt][nt];
    }

    // ---- region B: GEMM for nt2, nt3 INTERLEAVED with tanh/write of nt0,nt1.
    //      Odd kt iterations each carry one independent 4-elem tanh group;
    //      those chains depend only on region-A results, so they fill the
    //      MFMA shadow. ----
    #pragma unroll
    for (int kt = 0; kt < 8; ++kt){
      bf16x8 b2f = *(const bf16x8*)&sbR[browc + 2*(16*SBS) + kt*32 + q*8];
      bf16x8 b3f = *(const bf16x8*)&sbR[browc + 3*(16*SBS) + kt*32 + q*8];
      p[0][2] = __builtin_amdgcn_mfma_f32_16x16x32_bf16(Mf[0][kt], b2f, p[0][2], 0, 0, 0);
      p[1][2] = __builtin_amdgcn_mfma_f32_16x16x32_bf16(Mf[1][kt], b2f, p[1][2], 0, 0, 0);
      p[0][3] = __builtin_amdgcn_mfma_f32_16x16x32_bf16(Mf[0][kt], b3f, p[0][3], 0, 0, 0);
      p[1][3] = __builtin_amdgcn_mfma_f32_16x16x32_bf16(Mf[1][kt], b3f, p[1][3], 0, 0, 0);
      if (kt & 1){
        const int g  = kt >> 1;      // 0..3
        const int mt = g & 1;
        const int nt = g >> 1;       // 0 or 1
        floatx4 argv = Y[mt][nt] + p[mt][nt]*cin + gam[mt]*te;
        floatx4 zv;
        #pragma unroll
        for (int r = 0; r < 4; ++r) zv[r] = fast_tanh(argv[r]);
        w[mt][nt] = zv*wz + w[mt][nt];
        uint32x2 wv = { cvt_pk_bf16(zv[0], zv[1]), cvt_pk_bf16(zv[2], zv[3]) };
        *(uint32x2*)&sbW[browc + nt*(16*SBS) + n04 + mt*16] = wv;
      }
    }

    // ---- region C: bookkeeping + tanh + write for nt2, nt3 ----
    if (e == 0){
      #pragma unroll
      for (int mt = 0; mt < 2; ++mt)
        #pragma unroll
        for (int nt = 2; nt < 4; ++nt)
          Y[mt][nt] += dt6 * (sM[mt][nt] + p[mt][nt]);
    } else if (e == 1){
      #pragma unroll
      for (int mt = 0; mt < 2; ++mt)
        #pragma unroll
        for (int nt = 2; nt < 4; ++nt) sM[mt][nt] = p[mt][nt];
    } else {
      #pragma unroll
      for (int mt = 0; mt < 2; ++mt)
        #pragma unroll
        for (int nt = 2; nt < 4; ++nt) sM[mt][nt] += 2.0f * p[mt][nt];
    }
    #pragma unroll
    for (int mt = 0; mt < 2; ++mt)
      #pragma unroll
      for (int nt = 2; nt < 4; ++nt){
        floatx4 argv = Y[mt][nt] + p[mt][nt]*cin + gam[mt]*te;
        floatx4 zv;
        #pragma unroll
        for (int r = 0; r < 4; ++r) zv[r] = fast_tanh(argv[r]);
        w[mt][nt] = zv*wz + w[mt][nt];
        uint32x2 wv = { cvt_pk_bf16(zv[0], zv[1]), cvt_pk_bf16(zv[2], zv[3]) };
        *(uint32x2*)&sbW[browc + nt*(16*SBS) + n04 + mt*16] = wv;
      }
    __syncthreads();
  }

  // ---- epilogue: h_T = h0 + (dt6*w) @ W2 + b2, then out = h_T @ Wout ----
  // pack dt6*w -> SB0 (z_158 dead; its readers finished before slot-159 barrier)
  #pragma unroll
  for (int mt = 0; mt < 2; ++mt)
    #pragma unroll
    for (int nt = 0; nt < 4; ++nt){
      floatx4 wv4 = w[mt][nt] * dt6;
      uint32x2 wv = { cvt_pk_bf16(wv4[0], wv4[1]), cvt_pk_bf16(wv4[2], wv4[3]) };
      *(uint32x2*)&lds_sb0[browc + nt*(16*SBS) + n04 + mt*16] = wv;
    }
  __syncthreads();
  {
    bf16x8 W2f[2][8];
    #pragma unroll
    for (int mt = 0; mt < 2; ++mt)
      #pragma unroll
      for (int kt = 0; kt < 8; ++kt)
        W2f[mt][kt] = *(const bf16x8*)&W2Tg[arow[mt]*256 + kt*32 + q*8];
    floatx4 hF[2][4];
    #pragma unroll
    for (int mt = 0; mt < 2; ++mt){
      floatx4 b2v = *(const floatx4*)&b2[n04 + mt*16];
      #pragma unroll
      for (int nt = 0; nt < 4; ++nt) hF[mt][nt] = b2v;
    }
    #pragma unroll
    for (int kt = 0; kt < 8; ++kt){
      bf16x8 b[4];
      #pragma unroll
      for (int nt = 0; nt < 4; ++nt)
        b[nt] = *(const bf16x8*)&lds_sb0[browc + nt*(16*SBS) + kt*32 + q*8];
      #pragma unroll
      for (int mt = 0; mt < 2; ++mt)
        #pragma unroll
        for (int nt = 0; nt < 4; ++nt)
          hF[mt][nt] = __builtin_amdgcn_mfma_f32_16x16x32_bf16(W2f[mt][kt], b[nt], hF[mt][nt], 0, 0, 0);
    }
    // + h0, write h_T -> SB1
    #pragma unroll
    for (int mt = 0; mt < 2; ++mt)
      #pragma unroll
      for (int nt = 0; nt < 4; ++nt){
        bf16x4 h0v = *(const bf16x4*)&lds_h0[browc + nt*(16*SBS) + n04 + mt*16];
        #pragma unroll
        for (int r = 0; r < 4; ++r) hF[mt][nt][r] += bf2f(h0v[r]);
        uint32x2 wv = { cvt_pk_bf16(hF[mt][nt][0], hF[mt][nt][1]),
                        cvt_pk_bf16(hF[mt][nt][2], hF[mt][nt][3]) };
        *(uint32x2*)&lds_sb1[browc + nt*(16*SBS) + n04 + mt*16] = wv;
      }
  }
  __syncthreads();
  {
    const int r  = tid & 63;         // batch row within block
    const int og = tid >> 6;         // 8 groups; first 6 cover 18 outputs
    if (og < 6){
      const int obase = og * 3;
      float acc[3] = {0.f, 0.f, 0.f};
      for (int c = 0; c < 32; ++c){
        bf16x8 h8 = *(const bf16x8*)&lds_sb1[r*SBS + c*8];
        #pragma unroll
        for (int j = 0; j < 8; ++j){
          float hval = bf2f(h8[j]);
          int kk = c*8 + j;
          #pragma unroll
          for (int oo = 0; oo < 3; ++oo)
            acc[oo] += hval * Wout[kk*18 + obase + oo];
        }
      }
      #pragma unroll
      for (int oo = 0; oo < 3; ++oo)
        out[(size_t)(m0 + r)*18 + obase + oo] = acc[oo] + bout[obase + oo];
    }
  }
}

extern "C" void kernel_launch(void* const* d_in, const int* in_sizes, int n_in,
                              void* d_out, int out_size, void* d_ws, size_t ws_size,
                              hipStream_t stream){
  const float* x   = (const float*)d_in[0];
  const float* Ws  = (const float*)d_in[1];
  const float* bs  = (const float*)d_in[2];
  const float* W1  = (const float*)d_in[3];
  const float* b1  = (const float*)d_in[4];
  const float* W2  = (const float*)d_in[5];
  const float* b2  = (const float*)d_in[6];
  const float* Wo  = (const float*)d_in[7];
  const float* bo  = (const float*)d_in[8];
  float* out = (float*)d_out;

  __bf16* WsT  = (__bf16*)d_ws;          // 256x512 bf16 = 256 KB
  __bf16* W1T  = WsT + 512*256;          // 256x256 bf16 = 128 KB
  __bf16* W2T  = W1T + 256*256;          // 256x256 bf16 = 128 KB
  __bf16* MT   = W2T + 256*256;          // 256x256 bf16 = 128 KB
  float*  beta = (float*)(MT + 256*256); // 256 fp32 = 1 KB

  prep_kernel<<<128, 256, 0, stream>>>(Ws, W1, W2, b2, WsT, W1T, W2T, beta);
  prep_mt<<<256, 256, 0, stream>>>(W1, W2, MT);
  ode_kernel<<<256, 512, 0, stream>>>(x, bs, W1, b1, b2, Wo, bo,
                                      WsT, W1T, W2T, MT, beta, out);
}